// Round 14
// baseline (709.734 us; speedup 1.0000x reference)
//
#include <hip/hip_runtime.h>
#include <math.h>

#define LR 0.001f

// Sizes
#define B   64
#define IN  2048
#define HID 512
#define OUT 128
#define SPB 16            // slabs per sample
#define SLABQ 128         // q rows per slab
#define NBLK (B*SPB)      // 1024
#define NTHR 256

#define AQ __ATOMIC_ACQUIRE
#define RL __ATOMIC_RELEASE
#define SCP __HIP_MEMORY_SCOPE_AGENT

typedef float vf2 __attribute__((ext_vector_type(2)));
typedef float vf4 __attribute__((ext_vector_type(4)));

// coop ws layout (floats)
#define WS_ZPART 0                          // [64][16][512] = 524288
#define WS_ZOPP  (WS_ZPART + B*SPB*HID)     // [64][16][128] = 131072
#define WS_GBW   (WS_ZOPP + B*SPB*OUT)      // [64][512]     = 32768
#define WS_FLAGS (WS_GBW + B*HID)           // 3*2048 ints (padded counters)
// fallback layout (separate replay path; fully rewritten before reads)
#define FQC    16
#define FWS_ZP    0
#define FWS_TANH  (FWS_ZP + B*FQC*HID)
#define FWS_ZOP   (FWS_TANH + B*HID)
#define FWS_GB    (FWS_ZOP + B*8*OUT)

// out layout (floats)
#define O_L2N   0
#define O_DW0   (B*OUT)
#define O_DB0   (O_DW0 + B*IN*HID)
#define O_DW1   (O_DB0 + B*HID)
#define O_DB1   (O_DW1 + B*HID*OUT)

__device__ __forceinline__ void waitge(const int* p, int val) {
    while (__hip_atomic_load(p, AQ, SCP) < val) __builtin_amdgcn_s_sleep(8);
}

// LDS regions (floats), time-multiplexed:
//  fwd1:    x[0..128) | reduce[128..1152)
//  compute: zred[0..256) | sth[256..288) | zob[288..544) | g2[544..672) | sred[672..680)
//  upd0:    gb[0..512) | x[512..640)

__global__ __launch_bounds__(NTHR, 4)
void k_mega(const float* __restrict__ x, const float* __restrict__ ut,
            const float* __restrict__ W0, const float* __restrict__ bias0,
            const float* __restrict__ W1, const float* __restrict__ bias1,
            const float* __restrict__ dW0, const float* __restrict__ db0,
            const float* __restrict__ dW1, const float* __restrict__ db1,
            float* __restrict__ out, float* __restrict__ zpart,
            float* __restrict__ zop, float* __restrict__ gbw,
            int* __restrict__ flags) {
    __shared__ float lds[1280];
    const int bid = blockIdx.x, tid = threadIdx.x;
    const int b = bid >> 4, s = bid & 15;
    const int q0 = s * SLABQ;
    int* zcnt   = flags + b * 32;
    int* zopcnt = flags + 2048 + b * 32;
    int* gcnt   = flags + 4096 + b * 32;

    // ================= fwd1: z-partials for slab (b, s) =================
    if (tid < SLABQ) lds[tid] = x[b * IN + q0 + tid];
    __syncthreads();
    {
        const int sub = tid >> 7;              // 0..1 (64 q each)
        const int h = (tid & 127) << 2;
        const float* pW = W0 + (size_t)(q0 + sub * 64) * HID + h;
        const float* pD = dW0 + ((size_t)b * IN + q0 + sub * 64) * HID + h;
        const float* xs = lds + sub * 64;
        float4 a0 = make_float4(0.f, 0.f, 0.f, 0.f);
        float4 a1 = make_float4(0.f, 0.f, 0.f, 0.f);
        #pragma unroll 4
        for (int qi = 0; qi < 32; ++qi) {
            const float xa = xs[qi];
            const float xb = xs[qi + 32];
            const float4 wa = *(const float4*)(pW + (size_t)qi * HID);
            const float4 da = *(const float4*)(pD + (size_t)qi * HID);
            const float4 wb = *(const float4*)(pW + (size_t)(qi + 32) * HID);
            const float4 dbv = *(const float4*)(pD + (size_t)(qi + 32) * HID);
            a0.x += xa * (wa.x + da.x);  a0.y += xa * (wa.y + da.y);
            a0.z += xa * (wa.z + da.z);  a0.w += xa * (wa.w + da.w);
            a1.x += xb * (wb.x + dbv.x); a1.y += xb * (wb.y + dbv.y);
            a1.z += xb * (wb.z + dbv.z); a1.w += xb * (wb.w + dbv.w);
        }
        a0.x += a1.x; a0.y += a1.y; a0.z += a1.z; a0.w += a1.w;
        *(float4*)(lds + 128 + sub * 512 + h) = a0;
        __syncthreads();
        if (sub == 0) {
            const float4 r = *(float4*)(lds + 128 + 512 + h);
            a0.x += r.x; a0.y += r.y; a0.z += r.z; a0.w += r.w;
            *(float4*)(zpart + ((size_t)b * SPB + s) * HID + h) = a0;
        }
    }
    __syncthreads();
    __threadfence();
    if (tid == 0) {
        __hip_atomic_fetch_add(zcnt, 1, RL, SCP);
        waitge(zcnt, SPB);
    }
    __syncthreads();

    // ================= compute: 32-h slice hs = s*32 =================
    const int hs = s * 32;
    {   // tanh partial sums: thread (hl = tid&31, kk = tid>>5) sums 2 of 16 chunks
        const int hl = tid & 31, kk = tid >> 5;
        const float zsum = zpart[((size_t)b * SPB + kk) * HID + hs + hl]
                         + zpart[((size_t)b * SPB + kk + 8) * HID + hs + hl];
        lds[kk * 32 + hl] = zsum;
    }
    __syncthreads();
    if (tid < 32) {
        float z = 0.f;
        #pragma unroll
        for (int j = 0; j < 8; ++j) z += lds[j * 32 + tid];
        z += bias0[hs + tid] + db0[b * HID + hs + tid];
        lds[256 + tid] = tanhf(z);
    }
    __syncthreads();
    {   // zo partials over the slice: o = tid&127, hc = tid>>7 owns 16 h rows
        const int o = tid & 127, hc = tid >> 7;
        float acc = 0.f;
        #pragma unroll
        for (int k = 0; k < 16; ++k) {
            const int hl = hc * 16 + k;
            const int h = hs + hl;
            acc += lds[256 + hl] *
                   (W1[(size_t)h * OUT + o] + dW1[((size_t)b * HID + h) * OUT + o]);
        }
        lds[288 + tid] = acc;
    }
    __syncthreads();
    if (tid < 128)
        zop[((size_t)b * SPB + s) * OUT + tid] = lds[288 + tid] + lds[416 + tid];
    __syncthreads();
    __threadfence();
    if (tid == 0) {
        __hip_atomic_fetch_add(zopcnt, 1, RL, SCP);
        waitge(zopcnt, SPB);
    }
    __syncthreads();

    // stats + g2 (redundant per sibling block)
    if (tid < 128) {
        const int o = tid;
        float zo = bias1[o] + db1[b * OUT + o];
        #pragma unroll
        for (int k = 0; k < SPB; ++k) zo += zop[((size_t)b * SPB + k) * OUT + o];
        const float tr = ut[b * OUT + o];
        float a = zo * zo, c2 = tr * tr, d = tr * zo;
        for (int off = 32; off; off >>= 1) {
            a  += __shfl_xor(a,  off, 64);
            c2 += __shfl_xor(c2, off, 64);
            d  += __shfl_xor(d,  off, 64);
        }
        const int wv = tid >> 6;
        if ((tid & 63) == 0) {
            lds[672 + wv * 3] = a; lds[673 + wv * 3] = c2; lds[674 + wv * 3] = d;
        }
        lds[544 + o] = zo;
    }
    __syncthreads();
    const float l2  = lds[672] + lds[675];               // squared norm (as in source)
    const float ntv = fmaxf(sqrtf(lds[673] + lds[676]), 1e-12f);
    const float tdot = (lds[674] + lds[677]) / ntv;
    const float sc = 2.0f * tdot / (l2 * l2);
    if (tid < 128) {
        const int o = tid;
        const float zo = lds[544 + o];
        const float tr = ut[b * OUT + o];
        const float g2 = -(tr / ntv) / l2 + sc * zo;
        lds[544 + o] = g2;
        if (s == 0) {
            out[O_L2N + b * OUT + o] = zo / l2;
            out[O_DB1 + b * OUT + o] = db1[b * OUT + o] - LR * g2;
        }
    }
    __syncthreads();
    {   // bwd over slice: 4 waves x 8 h rows, lane owns 2 o
        const int wv = tid >> 6, lane = tid & 63, o2 = lane * 2;
        const float g2x = lds[544 + o2], g2y = lds[545 + o2];
        for (int i = 0; i < 8; ++i) {
            const int hl = wv * 8 + i;
            const int h = hs + hl;
            const size_t idx = ((size_t)b * HID + h) * OUT + o2;
            const float2 dw = *(const float2*)(dW1 + idx);
            const float2 w1v = *(const float2*)(W1 + (size_t)h * OUT + o2);
            float part = g2x * (w1v.x + dw.x) + g2y * (w1v.y + dw.y);
            for (int off = 32; off; off >>= 1) part += __shfl_xor(part, off, 64);
            const float th = lds[256 + hl];
            vf2 nd;
            nd.x = dw.x - LR * th * g2x;
            nd.y = dw.y - LR * th * g2y;
            __builtin_nontemporal_store(nd, (vf2*)(out + O_DW1 + idx));
            if (lane == 0) {
                const float gbv = (1.f - th * th) * part;
                gbw[(size_t)b * HID + h] = gbv;
                out[O_DB0 + b * HID + h] = db0[b * HID + h] - LR * gbv;
            }
        }
    }
    __syncthreads();
    __threadfence();
    if (tid == 0) {
        __hip_atomic_fetch_add(gcnt, 1, RL, SCP);
        waitge(gcnt, SPB);
    }
    __syncthreads();

    // ================= upd0: same slab this block fwd1'd (L3-hot) =================
    lds[tid] = gbw[(size_t)b * HID + tid];
    lds[256 + tid] = gbw[(size_t)b * HID + 256 + tid];
    if (tid < SLABQ) lds[512 + tid] = x[b * IN + q0 + tid];
    __syncthreads();
    {
        const size_t base4 = ((size_t)b * IN + q0) * (HID / 4);
        const float4* src = (const float4*)dW0;
        vf4* dst = (vf4*)(out + O_DW0);
        #pragma unroll 8
        for (int it = 0; it < 64; ++it) {
            const int i = it * NTHR + tid;
            const int ql = i >> 7, h4 = i & 127;
            const float4 dw = src[base4 + i];
            const float xv = lds[512 + ql];
            const float4 g = *(const float4*)&lds[h4 * 4];
            vf4 o4;
            o4.x = dw.x - LR * xv * g.x;
            o4.y = dw.y - LR * xv * g.y;
            o4.z = dw.z - LR * xv * g.z;
            o4.w = dw.w - LR * xv * g.w;
            __builtin_nontemporal_store(o4, dst + base4 + i);
        }
    }
}

// ===================== fallback (proven ~162 us) =====================

__global__ void k_fwd1f(const float* __restrict__ x, const float* __restrict__ W0,
                        const float* __restrict__ dW0, float* __restrict__ zp) {
    const int b = blockIdx.x;
    const int q0 = blockIdx.y * (IN / FQC);
    const int h = threadIdx.x * 4;
    const float* xr = x + b * IN;
    float4 acc = make_float4(0.f, 0.f, 0.f, 0.f);
    for (int qi = 0; qi < IN / FQC; ++qi) {
        const int q = q0 + qi;
        const float xv = xr[q];
        const float4 w0 = *(const float4*)(W0 + q * HID + h);
        const float4 dw = *(const float4*)(dW0 + ((size_t)(b * IN + q)) * HID + h);
        acc.x += xv * (w0.x + dw.x);
        acc.y += xv * (w0.y + dw.y);
        acc.z += xv * (w0.z + dw.z);
        acc.w += xv * (w0.w + dw.w);
    }
    *(float4*)(zp + (b * FQC + blockIdx.y) * HID + h) = acc;
}

__global__ void k_fwd2f(const float* __restrict__ zp, const float* __restrict__ b0,
                        const float* __restrict__ db0, const float* __restrict__ W1,
                        const float* __restrict__ dW1, float* __restrict__ tanhv,
                        float* __restrict__ zopf) {
    const int b = blockIdx.x;
    const int h0 = blockIdx.y * 64;
    const int tid = threadIdx.x;
    __shared__ float sth[64];
    if (tid < 64) {
        const int h = h0 + tid;
        float zsum = 0.f;
        #pragma unroll
        for (int qc = 0; qc < FQC; ++qc) zsum += zp[(b * FQC + qc) * HID + h];
        const float th = tanhf(zsum + b0[h] + db0[b * HID + h]);
        tanhv[b * HID + h] = th;
        sth[tid] = th;
    }
    __syncthreads();
    const int o = tid;
    float acc = 0.f;
    #pragma unroll 8
    for (int hi = 0; hi < 64; ++hi) {
        const int h = h0 + hi;
        acc += sth[hi] * (W1[h * OUT + o] + dW1[(b * HID + h) * OUT + o]);
    }
    zopf[(b * 8 + blockIdx.y) * OUT + o] = acc;
}

__global__ void k_bwd1f(const float* __restrict__ zopf, const float* __restrict__ b1,
                        const float* __restrict__ db1, const float* __restrict__ ut,
                        const float* __restrict__ W1, const float* __restrict__ dW1,
                        const float* __restrict__ tanhv, const float* __restrict__ db0,
                        float* __restrict__ out_l2n, float* __restrict__ out_db1,
                        float* __restrict__ out_dW1, float* __restrict__ out_db0,
                        float* __restrict__ gb) {
    const int b = blockIdx.x;
    const int w = threadIdx.x >> 6;
    const int lane = threadIdx.x & 63;
    const int o2 = lane * 2;
    float2 zo;
    zo.x = b1[o2]     + db1[b * OUT + o2];
    zo.y = b1[o2 + 1] + db1[b * OUT + o2 + 1];
    #pragma unroll
    for (int c = 0; c < 8; ++c) {
        const float2 zp2 = *(const float2*)(zopf + (b * 8 + c) * OUT + o2);
        zo.x += zp2.x; zo.y += zp2.y;
    }
    const float2 tr = *(const float2*)(ut + b * OUT + o2);
    float a = zo.x * zo.x + zo.y * zo.y;
    float c2 = tr.x * tr.x + tr.y * tr.y;
    float d  = tr.x * zo.x + tr.y * zo.y;
    for (int off = 32; off; off >>= 1) {
        a  += __shfl_xor(a,  off, 64);
        c2 += __shfl_xor(c2, off, 64);
        d  += __shfl_xor(d,  off, 64);
    }
    const float l2 = a;
    const float nt = fmaxf(sqrtf(c2), 1e-12f);
    const float tdot = d / nt;
    const float s = 2.0f * tdot / (l2 * l2);
    float2 g2;
    g2.x = -(tr.x / nt) / l2 + s * zo.x;
    g2.y = -(tr.y / nt) / l2 + s * zo.y;
    if (blockIdx.y == 0 && w == 0) {
        *(float2*)(out_l2n + b * OUT + o2) = make_float2(zo.x / l2, zo.y / l2);
        *(float2*)(out_db1 + b * OUT + o2) =
            make_float2(db1[b * OUT + o2] - LR * g2.x, db1[b * OUT + o2 + 1] - LR * g2.y);
    }
    for (int i = 0; i < 16; ++i) {
        const int h = blockIdx.y * 64 + w * 16 + i;
        const int idx = (b * HID + h) * OUT + o2;
        const float2 dw = *(const float2*)(dW1 + idx);
        const float2 w1v = *(const float2*)(W1 + h * OUT + o2);
        float part = g2.x * (w1v.x + dw.x) + g2.y * (w1v.y + dw.y);
        for (int off = 32; off; off >>= 1) part += __shfl_xor(part, off, 64);
        const float th = tanhv[b * HID + h];
        vf2 nd;
        nd.x = dw.x - LR * th * g2.x;
        nd.y = dw.y - LR * th * g2.y;
        __builtin_nontemporal_store(nd, (vf2*)(out_dW1 + idx));
        if (lane == 0) {
            const float gbv = (1.f - th * th) * part;
            gb[b * HID + h] = gbv;
            out_db0[b * HID + h] = db0[b * HID + h] - LR * gbv;
        }
    }
}

__global__ void k_upd0f(const float* __restrict__ dW0, const float* __restrict__ x,
                        const float* __restrict__ gb, float* __restrict__ out_dW0) {
    const int n4 = B * IN * HID / 4;
    const int stride = gridDim.x * blockDim.x;
    for (int i = blockIdx.x * blockDim.x + threadIdx.x; i < n4; i += stride) {
        const int j = n4 - 1 - i;
        const int h4 = j & (HID / 4 - 1);
        const int rest = j >> 7;
        const int q = rest & (IN - 1);
        const int b = rest >> 11;
        const float4 dw = ((const float4*)dW0)[j];
        const float xv = x[b * IN + q];
        const float4 g = *(const float4*)(gb + b * HID + h4 * 4);
        vf4 o;
        o.x = dw.x - LR * xv * g.x;
        o.y = dw.y - LR * xv * g.y;
        o.z = dw.z - LR * xv * g.z;
        o.w = dw.w - LR * xv * g.w;
        __builtin_nontemporal_store(o, (vf4*)out_dW0 + j);
    }
}

extern "C" void kernel_launch(void* const* d_in, const int* in_sizes, int n_in,
                              void* d_out, int out_size, void* d_ws, size_t ws_size,
                              hipStream_t stream) {
    (void)in_sizes; (void)n_in; (void)out_size; (void)ws_size;
    const float* x   = (const float*)d_in[0];
    const float* ut  = (const float*)d_in[1];
    const float* W0  = (const float*)d_in[2];
    const float* b0  = (const float*)d_in[3];
    const float* W1  = (const float*)d_in[4];
    const float* b1  = (const float*)d_in[5];
    const float* dW0 = (const float*)d_in[6];
    const float* db0 = (const float*)d_in[7];
    const float* dW1 = (const float*)d_in[8];
    const float* db1 = (const float*)d_in[9];

    float* ws  = (float*)d_ws;
    float* out = (float*)d_out;
    float* zpart = ws + WS_ZPART;
    float* zop   = ws + WS_ZOPP;
    float* gbw   = ws + WS_GBW;
    int*   flags = (int*)(ws + WS_FLAGS);

    // zero padded counters every replay (graph-capturable)
    hipMemsetAsync(flags, 0, 3 * 2048 * sizeof(int), stream);

    void* args[] = {(void*)&x, (void*)&ut, (void*)&W0, (void*)&b0, (void*)&W1,
                    (void*)&b1, (void*)&dW0, (void*)&db0, (void*)&dW1, (void*)&db1,
                    (void*)&out, (void*)&zpart, (void*)&zop, (void*)&gbw,
                    (void*)&flags};
    hipError_t err = hipLaunchCooperativeKernel((void*)k_mega, dim3(NBLK), dim3(NTHR),
                                                args, 0, stream);
    if (err != hipSuccess) {
        (void)hipGetLastError();
        k_fwd1f<<<dim3(B, FQC), 128, 0, stream>>>(x, W0, dW0, ws + FWS_ZP);
        k_fwd2f<<<dim3(B, 8), 128, 0, stream>>>(ws + FWS_ZP, b0, db0, W1, dW1,
                                                ws + FWS_TANH, ws + FWS_ZOP);
        k_bwd1f<<<dim3(B, 8), 256, 0, stream>>>(ws + FWS_ZOP, b1, db1, ut, W1, dW1,
                                                ws + FWS_TANH, db0,
                                                out + O_L2N, out + O_DB1,
                                                out + O_DW1, out + O_DB0, ws + FWS_GB);
        k_upd0f<<<dim3(4096), 256, 0, stream>>>(dW0, x, ws + FWS_GB, out + O_DW0);
    }
}

// Round 15
// 186.245 us; speedup vs baseline: 3.8108x; 3.8108x over previous
//
#include <hip/hip_runtime.h>
#include <math.h>

#define LR 0.001f

// Sizes
#define B   64
#define IN  2048
#define HID 512
#define OUT 128
#define QC  16          // q-chunks for layer-1 partials

typedef float vf2 __attribute__((ext_vector_type(2)));
typedef float vf4 __attribute__((ext_vector_type(4)));

// ws layout (floats)
#define WS_ZP    0                       // [B][QC][HID] = 524288
#define WS_GB    (WS_ZP + B*QC*HID)      // [B][HID]     = 32768

// out layout (floats)
#define O_L2N   0
#define O_DW0   (B*OUT)
#define O_DB0   (O_DW0 + B*IN*HID)
#define O_DW1   (O_DB0 + B*HID)
#define O_DB1   (O_DW1 + B*HID*OUT)

// ---- layer-1 forward partials: zp[b,qc,h] = sum_{q in chunk} x[b,q]*(W0[q,h]+dW0[b,q,h])
// grid (B, QC), block 128; thread owns 4 h (float4), block owns 128 q rows.
// (verbatim from the proven 161.6 us kernel)
__global__ void k_fwd1(const float* __restrict__ x, const float* __restrict__ W0,
                       const float* __restrict__ dW0, float* __restrict__ zp) {
    const int b = blockIdx.x;
    const int q0 = blockIdx.y * (IN / QC);
    const int h = threadIdx.x * 4;        // 0..508
    const float* xr = x + b * IN;
    float4 acc = make_float4(0.f, 0.f, 0.f, 0.f);
    for (int qi = 0; qi < IN / QC; ++qi) {
        const int q = q0 + qi;
        const float xv = xr[q];
        const float4 w0 = *(const float4*)(W0 + q * HID + h);
        const float4 dw = *(const float4*)(dW0 + ((size_t)(b * IN + q)) * HID + h);
        acc.x += xv * (w0.x + dw.x);
        acc.y += xv * (w0.y + dw.y);
        acc.z += xv * (w0.z + dw.z);
        acc.w += xv * (w0.w + dw.w);
    }
    *(float4*)(zp + (b * QC + blockIdx.y) * HID + h) = acc;
}

// ---- merged middle: tanh + zo + stats + g2 + bwd1 (+ all small outputs)
// grid B, block 512 (8 waves); per-sample state entirely in LDS.
// dW1[b] slice (256 KB) is read in phase B and re-read in phase D while L2-hot.
__global__ __launch_bounds__(512, 2)
void k_mid(const float* __restrict__ zp, const float* __restrict__ bias0,
           const float* __restrict__ db0, const float* __restrict__ W1,
           const float* __restrict__ bias1, const float* __restrict__ db1,
           const float* __restrict__ ut, const float* __restrict__ dW1,
           float* __restrict__ out_l2n, float* __restrict__ out_db1,
           float* __restrict__ out_dW1, float* __restrict__ out_db0,
           float* __restrict__ gb) {
    __shared__ float sth[HID];      // tanh
    __shared__ float red[HID];      // zo partials (4 x 128)
    __shared__ float sg2[OUT];      // zo, then g2
    __shared__ float sred[8];
    const int b = blockIdx.x;
    const int tid = threadIdx.x;

    // A: z-sum over QC chunks + bias + tanh (one h per thread)
    {
        float zs = 0.f;
        const float* p = zp + (size_t)(b * QC) * HID + tid;
        #pragma unroll
        for (int qc = 0; qc < QC; ++qc) zs += p[qc * HID];
        sth[tid] = tanhf(zs + bias0[tid] + db0[b * HID + tid]);
    }
    __syncthreads();

    // B: zo partials: hc = tid>>7 owns 128 h rows, o = tid&127
    {
        const int hc = tid >> 7, o = tid & 127;
        const float* pw = W1 + (size_t)(hc * 128) * OUT + o;
        const float* pd = dW1 + ((size_t)b * HID + hc * 128) * OUT + o;
        const float* st = sth + hc * 128;
        float acc = 0.f;
        #pragma unroll 8
        for (int k = 0; k < 128; ++k)
            acc += st[k] * (pw[k * OUT] + pd[k * OUT]);
        red[hc * 128 + o] = acc;
    }
    __syncthreads();

    // C: stats + g2 (tid < 128, two waves)
    if (tid < 128) {
        const int o = tid;
        const float zo = red[o] + red[128 + o] + red[256 + o] + red[384 + o]
                       + bias1[o] + db1[b * OUT + o];
        const float tr = ut[b * OUT + o];
        float a = zo * zo, c2 = tr * tr, d = tr * zo;
        for (int off = 32; off; off >>= 1) {
            a  += __shfl_xor(a,  off, 64);
            c2 += __shfl_xor(c2, off, 64);
            d  += __shfl_xor(d,  off, 64);
        }
        const int wv = tid >> 6;
        if ((tid & 63) == 0) { sred[wv*3] = a; sred[wv*3+1] = c2; sred[wv*3+2] = d; }
        sg2[o] = zo;
    }
    __syncthreads();
    const float l2  = sred[0] + sred[3];                 // squared norm (as in source)
    const float ntv = fmaxf(sqrtf(sred[1] + sred[4]), 1e-12f);
    const float tdot = (sred[2] + sred[5]) / ntv;
    const float sc = 2.0f * tdot / (l2 * l2);
    if (tid < 128) {
        const int o = tid;
        const float zo = sg2[o];
        const float tr = ut[b * OUT + o];
        const float g2 = -(tr / ntv) / l2 + sc * zo;
        sg2[o] = g2;
        out_l2n[b * OUT + o] = zo / l2;
        out_db1[b * OUT + o] = db1[b * OUT + o] - LR * g2;
    }
    __syncthreads();

    // D: bwd through layer 2: 8 waves x 64 h rows, lane owns 2 o
    {
        const int wv = tid >> 6, lane = tid & 63, o2 = lane * 2;
        const float g2x = sg2[o2], g2y = sg2[o2 + 1];
        for (int i = 0; i < 64; ++i) {
            const int h = wv * 64 + i;
            const size_t idx = ((size_t)b * HID + h) * OUT + o2;
            const float2 dw = *(const float2*)(dW1 + idx);
            const float2 w1 = *(const float2*)(W1 + h * OUT + o2);
            float part = g2x * (w1.x + dw.x) + g2y * (w1.y + dw.y);
            for (int off = 32; off; off >>= 1) part += __shfl_xor(part, off, 64);
            const float th = sth[h];
            vf2 nd;
            nd.x = dw.x - LR * th * g2x;
            nd.y = dw.y - LR * th * g2y;
            __builtin_nontemporal_store(nd, (vf2*)(out_dW1 + idx));
            if (lane == 0) {
                const float gbv = (1.f - th * th) * part;
                gb[b * HID + h] = gbv;
                out_db0[b * HID + h] = db0[b * HID + h] - LR * gbv;
            }
        }
    }
}

// ---- new_d_weights_0 = dW0 - LR * x[b,q] * gb[b,h]
// REVERSED traversal + plain loads + NT stores (verbatim from the proven kernel).
__global__ void k_upd0(const float* __restrict__ dW0, const float* __restrict__ x,
                       const float* __restrict__ gb, float* __restrict__ out_dW0) {
    const int n4 = B * IN * HID / 4;     // 16,777,216
    const int stride = gridDim.x * blockDim.x;
    for (int i = blockIdx.x * blockDim.x + threadIdx.x; i < n4; i += stride) {
        const int j = n4 - 1 - i;                // reversed (ride L3 residency)
        const int h4 = j & (HID / 4 - 1);        // 0..127
        const int rest = j >> 7;
        const int q = rest & (IN - 1);
        const int b = rest >> 11;
        const float4 dw = ((const float4*)dW0)[j];
        const float xv = x[b * IN + q];
        const float4 g = *(const float4*)(gb + b * HID + h4 * 4);
        vf4 o;
        o.x = dw.x - LR * xv * g.x;
        o.y = dw.y - LR * xv * g.y;
        o.z = dw.z - LR * xv * g.z;
        o.w = dw.w - LR * xv * g.w;
        __builtin_nontemporal_store(o, (vf4*)out_dW0 + j);
    }
}

extern "C" void kernel_launch(void* const* d_in, const int* in_sizes, int n_in,
                              void* d_out, int out_size, void* d_ws, size_t ws_size,
                              hipStream_t stream) {
    (void)in_sizes; (void)n_in; (void)out_size; (void)ws_size;
    const float* x   = (const float*)d_in[0];
    const float* ut  = (const float*)d_in[1];
    const float* W0  = (const float*)d_in[2];
    const float* b0  = (const float*)d_in[3];
    const float* W1  = (const float*)d_in[4];
    const float* b1  = (const float*)d_in[5];
    const float* dW0 = (const float*)d_in[6];
    const float* db0 = (const float*)d_in[7];
    const float* dW1 = (const float*)d_in[8];
    const float* db1 = (const float*)d_in[9];

    float* ws  = (float*)d_ws;
    float* out = (float*)d_out;

    k_fwd1<<<dim3(B, QC), 128, 0, stream>>>(x, W0, dW0, ws + WS_ZP);
    k_mid<<<dim3(B), 512, 0, stream>>>(ws + WS_ZP, b0, db0, W1, b1, db1, ut, dW1,
                                       out + O_L2N, out + O_DB1,
                                       out + O_DW1, out + O_DB0, ws + WS_GB);
    k_upd0<<<dim3(4096), 256, 0, stream>>>(dW0, x, ws + WS_GB, out + O_DW0);
}